// Round 1
// 268.007 us; speedup vs baseline: 1.0286x; 1.0286x over previous
//
#include <hip/hip_runtime.h>
#include <stdint.h>

#define HIDDEN 1024
#define BATCH  4
#define SEQ    2048
#define TOKENS (BATCH * SEQ)      // 8192
#define QKVD   (3 * HIDDEN)       // 3072

typedef unsigned short u16;
typedef __attribute__((ext_vector_type(8))) short   short8;   // 8 bf16 = 4 VGPRs
typedef __attribute__((ext_vector_type(4))) float   floatx4;

// deterministic round-to-nearest-even f32 -> bf16 (no NaN inputs here)
__device__ __forceinline__ u16 f32_bf16_rne(float f) {
    unsigned int u = __float_as_uint(f);
    u += 0x7FFFu + ((u >> 16) & 1u);
    return (u16)(u >> 16);
}

// async global->LDS, 16B per lane. LDS dest is wave-uniform base + lane*16.
__device__ __forceinline__ void gl16(const u16* g, u16* l) {
    __builtin_amdgcn_global_load_lds(
        (const __attribute__((address_space(1))) void*)g,
        (__attribute__((address_space(3))) void*)l, 16, 0, 0);
}

// Counted-vmcnt sync: wait until only the newest 3 staging loads (one
// half-tile set: A-slab 1 + B-slab 2) remain in flight, then barrier.
// NEVER vmcnt(0) in the main loop (T4). sched_barrier(0) pins the phase's
// MFMAs + their lgkm waits before the barrier (rule #18 class hazard).
#define SYNC3() do { __builtin_amdgcn_sched_barrier(0); \
    asm volatile("s_waitcnt vmcnt(3)\n\ts_barrier" ::: "memory"); } while (0)

// ---------------------------------------------------------------- convert
__global__ __launch_bounds__(256) void cvt_bf16_kernel(
        const float* __restrict__ src, u16* __restrict__ dst, int n4) {
    int i = blockIdx.x * 256 + threadIdx.x;
    if (i >= n4) return;
    float4 v = ((const float4*)src)[i];
    ushort4 o;
    o.x = f32_bf16_rne(v.x); o.y = f32_bf16_rne(v.y);
    o.z = f32_bf16_rne(v.z); o.w = f32_bf16_rne(v.w);
    ((ushort4*)dst)[i] = o;
}

// ---------------------------------------------------------------- GEMM (NT)
// C[M,N] = A[M,K] * B[N,K]^T.  BM=128, BN=256, BK=64. 512 threads = 8 waves
// (2M x 4N), per-wave 64x64 via 4x4 grid of 16x16x32 bf16 MFMA.
//
// Round 7: 4-phase counted-vmcnt pipeline (T3+T4+T5 from the 8-phase
// template, adapted to K-slab granularity):
//   LDS = [buf:2][ks:2]{ A[128 rows][32 k] | B[256 rows][32 k] }  (96 KB)
//   Slab rows are 64 B; 16B slots XOR-swizzled: phys_slot = slot ^ ((r>>1)&3)
//   -> wave64 ds_read_b128 of a fragment is 2-way (free) instead of 8-way.
//   Staged DIRECTLY with global_load_lds (linear dest, inverse-swizzled
//   global source), one slab per phase:
//     P0: stage A_ks0(t+1) | read B_ks0 + A(mi0,1) | 8 MFMA
//     P1: stage B_ks0(t+1) | read A(mi2,3)         | 8 MFMA   SYNC vmcnt(3)
//     P2: stage A_ks1(t+1) | read B_ks1 + A(mi0,1) | 8 MFMA
//     P3: stage B_ks1(t+1) | read A(mi2,3)         | 8 MFMA   SYNC vmcnt(3)
//   At each sync exactly 3 loads (the newest half-tile set) stay in flight
//   across the barrier; the 3 waited-on are exactly the slabs the next two
//   phases read. Stage buffer != read buffer inside every barrier window.
//
// EPI: 0 = bf16 store + bias[col]; 1 = f32 store * scale; 2 = f32 store.
template <int EPI>
__global__ __launch_bounds__(512, 2) void gemm_bt(
        const u16* __restrict__ A, const u16* __restrict__ B,
        void* __restrict__ Cv, const float* __restrict__ bias,
        int K, int lda, int ldb, int ldc,
        size_t sA, size_t sB, size_t sC, float scale) {
    // [buf][ks][ A: 128*32 = 4096 u16 | B: 256*32 = 8192 u16 ]  = 96 KB
    __shared__ __align__(16) u16 lds[2][2][(128 + 256) * 32];

    const int t    = threadIdx.x;
    const int lane = t & 63;
    const int wid  = t >> 6;             // 0..7
    const int wr   = wid >> 2;           // 0..1  (M)
    const int wc   = wid & 3;            // 0..3  (N)
    const int bm   = blockIdx.y * 128;
    const int bn   = blockIdx.x * 256;

    const u16* Ab = A + (size_t)blockIdx.z * sA;
    const u16* Bb = B + (size_t)blockIdx.z * sB;

    // ---- staging source (per thread). Linear LDS dest offset = t*16 B
    // within a slab -> row r = t>>2 (64 B rows), phys slot = t&3. The data
    // for phys slot p of row r comes from global slot p ^ ((r>>1)&3).
    const int rA   = t >> 2;                              // 0..127
    const int slA  = (t & 3) ^ ((rA >> 1) & 3);
    const u16* gA  = Ab + (size_t)(bm + rA) * lda + slA * 8;
    const int rB   = t >> 2;                              // 0..127 (+128 for 2nd)
    const int slB  = (t & 3) ^ ((rB >> 1) & 3);           // same for r+128
    const u16* gB0 = Bb + (size_t)(bn + rB) * ldb + slB * 8;
    const u16* gB1 = gB0 + (size_t)128 * ldb;

    // ---- fragment read geometry (same MFMA conventions as prior rounds)
    const int fr = lane & 15;            // row-in-16 of A/B fragment
    const int kc = lane >> 4;            // 16B k-chunk 0..3
    const int sw = (fr >> 1) & 3;        // swizzle term (row-dependent part)
    const int fo = (kc ^ sw) << 4;       // phys slot byte offset
    const int aoffB = (wr * 64 + fr) * 64 + fo;   // bytes into A slab
    const int boffB = (wc * 64 + fr) * 64 + fo;   // bytes into B slab

    floatx4 acc[4][4];
#pragma unroll
    for (int i = 0; i < 4; i++)
#pragma unroll
        for (int j = 0; j < 4; j++) acc[i][j] = (floatx4){0.f, 0.f, 0.f, 0.f};

    short8 bfr0, bfr1, bfr2, bfr3, va0, va1;

#define LDB4(BASE) \
    bfr0 = *(const short8*)((BASE) + boffB);        \
    bfr1 = *(const short8*)((BASE) + boffB + 1024); \
    bfr2 = *(const short8*)((BASE) + boffB + 2048); \
    bfr3 = *(const short8*)((BASE) + boffB + 3072);

#define MFMA2(MI, A0, A1) \
    __builtin_amdgcn_s_setprio(1); \
    acc[MI][0]     = __builtin_amdgcn_mfma_f32_16x16x32_bf16(A0, bfr0, acc[MI][0], 0, 0, 0); \
    acc[MI][1]     = __builtin_amdgcn_mfma_f32_16x16x32_bf16(A0, bfr1, acc[MI][1], 0, 0, 0); \
    acc[MI][2]     = __builtin_amdgcn_mfma_f32_16x16x32_bf16(A0, bfr2, acc[MI][2], 0, 0, 0); \
    acc[MI][3]     = __builtin_amdgcn_mfma_f32_16x16x32_bf16(A0, bfr3, acc[MI][3], 0, 0, 0); \
    acc[(MI)+1][0] = __builtin_amdgcn_mfma_f32_16x16x32_bf16(A1, bfr0, acc[(MI)+1][0], 0, 0, 0); \
    acc[(MI)+1][1] = __builtin_amdgcn_mfma_f32_16x16x32_bf16(A1, bfr1, acc[(MI)+1][1], 0, 0, 0); \
    acc[(MI)+1][2] = __builtin_amdgcn_mfma_f32_16x16x32_bf16(A1, bfr2, acc[(MI)+1][2], 0, 0, 0); \
    acc[(MI)+1][3] = __builtin_amdgcn_mfma_f32_16x16x32_bf16(A1, bfr3, acc[(MI)+1][3], 0, 0, 0); \
    __builtin_amdgcn_s_setprio(0);

#define ITER(BUF, SBUF, SCOL) { \
    const char* As0_ = (const char*)&lds[BUF][0][0]; \
    const char* Bs0_ = As0_ + 8192; \
    const char* As1_ = (const char*)&lds[BUF][1][0]; \
    const char* Bs1_ = As1_ + 8192; \
    /* P0: stage A_ks0(next) ; compute mi0,1 x ks0 */ \
    gl16(gA + (SCOL),       (u16*)((char*)&lds[SBUF][0][0]    + wid * 1024)); \
    LDB4(Bs0_); \
    va0 = *(const short8*)(As0_ + aoffB); \
    va1 = *(const short8*)(As0_ + aoffB + 1024); \
    MFMA2(0, va0, va1); \
    /* P1: stage B_ks0(next) ; compute mi2,3 x ks0 */ \
    gl16(gB0 + (SCOL),      (u16*)((char*)&lds[SBUF][0][4096] + wid * 1024)); \
    gl16(gB1 + (SCOL),      (u16*)((char*)&lds[SBUF][0][8192] + wid * 1024)); \
    va0 = *(const short8*)(As0_ + aoffB + 2048); \
    va1 = *(const short8*)(As0_ + aoffB + 3072); \
    MFMA2(2, va0, va1); \
    SYNC3(); \
    /* P2: stage A_ks1(next) ; compute mi0,1 x ks1 */ \
    gl16(gA + (SCOL) + 32,  (u16*)((char*)&lds[SBUF][1][0]    + wid * 1024)); \
    LDB4(Bs1_); \
    va0 = *(const short8*)(As1_ + aoffB); \
    va1 = *(const short8*)(As1_ + aoffB + 1024); \
    MFMA2(0, va0, va1); \
    /* P3: stage B_ks1(next) ; compute mi2,3 x ks1 */ \
    gl16(gB0 + (SCOL) + 32, (u16*)((char*)&lds[SBUF][1][4096] + wid * 1024)); \
    gl16(gB1 + (SCOL) + 32, (u16*)((char*)&lds[SBUF][1][8192] + wid * 1024)); \
    va0 = *(const short8*)(As1_ + aoffB + 2048); \
    va1 = *(const short8*)(As1_ + aoffB + 3072); \
    MFMA2(2, va0, va1); \
    SYNC3(); }

    // prologue: stage tile 0 -> buf0 in steady-state order (ks0 set, ks1 set);
    // SYNC3 waits the ks0 set, leaves the ks1 set in flight (= steady state).
    gl16(gA,       (u16*)((char*)&lds[0][0][0]    + wid * 1024));
    gl16(gB0,      (u16*)((char*)&lds[0][0][4096] + wid * 1024));
    gl16(gB1,      (u16*)((char*)&lds[0][0][8192] + wid * 1024));
    gl16(gA + 32,  (u16*)((char*)&lds[0][1][0]    + wid * 1024));
    gl16(gB0 + 32, (u16*)((char*)&lds[0][1][4096] + wid * 1024));
    gl16(gB1 + 32, (u16*)((char*)&lds[0][1][8192] + wid * 1024));
    SYNC3();

    const int nk = K >> 6;               // 64-wide K-tiles (16 or 32 here)
    for (int kt = 0; kt < nk; kt += 2) {
        const int c1 = (kt + 1) * 64;
        const int c2 = (kt + 2 < nk ? (kt + 2) : (nk - 1)) * 64;  // tail restage, harmless
        ITER(0, 1, c1)
        ITER(1, 0, c2)
    }
    // drain dangling tail restage before the block retires
    asm volatile("s_waitcnt vmcnt(0)" ::: "memory");

#undef ITER
#undef MFMA2
#undef LDB4

    // epilogue: C/D 16x16 mapping col=lane&15, row=(lane>>4)*4+reg
    const int crow0 = bm + wr * 64 + kc * 4;
    const int ccol0 = bn + wc * 64 + fr;
    const size_t coff = (size_t)blockIdx.z * sC;

    if (EPI == 0) {
        u16* C = (u16*)Cv;
        float bv[4];
#pragma unroll
        for (int ni = 0; ni < 4; ni++) bv[ni] = bias[ccol0 + ni * 16];
#pragma unroll
        for (int mi = 0; mi < 4; mi++)
#pragma unroll
            for (int ni = 0; ni < 4; ni++)
#pragma unroll
                for (int r = 0; r < 4; r++)
                    C[coff + (size_t)(crow0 + mi * 16 + r) * ldc + (ccol0 + ni * 16)] =
                        f32_bf16_rne(acc[mi][ni][r] + bv[ni]);
    } else {
        float* C = (float*)Cv;
#pragma unroll
        for (int mi = 0; mi < 4; mi++)
#pragma unroll
            for (int ni = 0; ni < 4; ni++)
#pragma unroll
                for (int r = 0; r < 4; r++) {
                    float v = acc[mi][ni][r];
                    if (EPI == 1) v *= scale;
                    C[coff + (size_t)(crow0 + mi * 16 + r) * ldc + (ccol0 + ni * 16)] = v;
                }
    }
}

// ---------------------------------------------------------------- softmax
// one block per row; 2048 fp32 scores (already scaled) -> 2048 bf16 probs
__global__ __launch_bounds__(256) void softmax_kernel(
        const float* __restrict__ S, u16* __restrict__ P) {
    __shared__ float redm[4];
    __shared__ float reds[4];
    const size_t base = (size_t)blockIdx.x * SEQ;
    const int t = threadIdx.x, lane = t & 63, wid = t >> 6;
    const float4* src = (const float4*)(S + base);
    float4 a = src[t], b = src[t + 256];

    float m = fmaxf(fmaxf(fmaxf(a.x, a.y), fmaxf(a.z, a.w)),
                    fmaxf(fmaxf(b.x, b.y), fmaxf(b.z, b.w)));
#pragma unroll
    for (int off = 32; off; off >>= 1) m = fmaxf(m, __shfl_xor(m, off, 64));
    if (lane == 0) redm[wid] = m;
    __syncthreads();
    m = fmaxf(fmaxf(redm[0], redm[1]), fmaxf(redm[2], redm[3]));

    float e[8];
    e[0] = __expf(a.x - m); e[1] = __expf(a.y - m);
    e[2] = __expf(a.z - m); e[3] = __expf(a.w - m);
    e[4] = __expf(b.x - m); e[5] = __expf(b.y - m);
    e[6] = __expf(b.z - m); e[7] = __expf(b.w - m);
    float s = e[0] + e[1] + e[2] + e[3] + e[4] + e[5] + e[6] + e[7];
#pragma unroll
    for (int off = 32; off; off >>= 1) s += __shfl_xor(s, off, 64);
    if (lane == 0) reds[wid] = s;
    __syncthreads();
    s = reds[0] + reds[1] + reds[2] + reds[3];
    const float r = 1.f / s;

    ushort4* dst = (ushort4*)(P + base);
    ushort4 o0, o1;
    o0.x = f32_bf16_rne(e[0] * r); o0.y = f32_bf16_rne(e[1] * r);
    o0.z = f32_bf16_rne(e[2] * r); o0.w = f32_bf16_rne(e[3] * r);
    o1.x = f32_bf16_rne(e[4] * r); o1.y = f32_bf16_rne(e[5] * r);
    o1.z = f32_bf16_rne(e[6] * r); o1.w = f32_bf16_rne(e[7] * r);
    dst[t] = o0;
    dst[t + 256] = o1;
}

// ---------------------------------------------------------------- V transpose
// Vt[b][h][s] <- qkv[b*SEQ+s][2*HIDDEN+h], 64x64 LDS tiles, pad 66 (bank-safe)
__global__ __launch_bounds__(256) void transposeV_kernel(
        const u16* __restrict__ qkv, u16* __restrict__ Vt) {
    __shared__ u16 tile[64][66];
    const int b = blockIdx.z;
    const int s0 = blockIdx.x * 64, h0 = blockIdx.y * 64;
    const int t = threadIdx.x;
    const int c = t & 63, r4 = t >> 6;
#pragma unroll
    for (int i = 0; i < 16; i++) {
        int sl = i * 4 + r4;
        tile[sl][c] = qkv[(size_t)(b * SEQ + s0 + sl) * QKVD + 2 * HIDDEN + h0 + c];
    }
    __syncthreads();
#pragma unroll
    for (int i = 0; i < 16; i++) {
        int hl = i * 4 + r4;
        Vt[(size_t)(b * HIDDEN + h0 + hl) * SEQ + s0 + c] = tile[c][hl];
    }
}

// ---------------------------------------------------------------- launch
extern "C" void kernel_launch(void* const* d_in, const int* in_sizes, int n_in,
                              void* d_out, int out_size, void* d_ws, size_t ws_size,
                              hipStream_t stream) {
    const float* x    = (const float*)d_in[0];   // [4,2048,1024]
    const float* W    = (const float*)d_in[1];   // [3072,1024]
    const float* bias = (const float*)d_in[2];   // [3072]
    float* out = (float*)d_out;                  // [4,2048,1024]

    // workspace layout (191 MB total)
    u16* Xb  = (u16*)d_ws;                                  // 8192x1024 bf16
    u16* Wb  = Xb + (size_t)TOKENS * HIDDEN;                // 3072x1024 bf16
    u16* qkv = Wb + (size_t)QKVD * HIDDEN;                  // 8192x3072 bf16
    float* scores = (float*)(qkv + (size_t)TOKENS * QKVD);  // 4x2048x2048 f32
    u16* P  = (u16*)(scores + (size_t)BATCH * SEQ * SEQ);   // 4x2048x2048 bf16
    u16* Vt = P + (size_t)BATCH * SEQ * SEQ;                // 4x1024x2048 bf16

    // 1) fp32 -> bf16 casts
    cvt_bf16_kernel<<<TOKENS * HIDDEN / 4 / 256, 256, 0, stream>>>(x, Xb, TOKENS * HIDDEN / 4);
    cvt_bf16_kernel<<<QKVD * HIDDEN / 4 / 256, 256, 0, stream>>>(W, Wb, QKVD * HIDDEN / 4);

    // 2) QKV projection: qkv = Xb @ Wb^T + bias  (bf16 out)  grid 12x64 = 768
    gemm_bt<0><<<dim3(QKVD / 256, TOKENS / 128, 1), 512, 0, stream>>>(
        Xb, Wb, qkv, bias, HIDDEN, HIDDEN, HIDDEN, QKVD, 0, 0, 0, 1.f);

    // 3) scores = scale * Q @ K^T per batch (f32 out)  grid 8x16x4 = 512
    gemm_bt<1><<<dim3(SEQ / 256, SEQ / 128, BATCH), 512, 0, stream>>>(
        qkv, qkv + HIDDEN, scores, nullptr, HIDDEN, QKVD, QKVD, SEQ,
        (size_t)SEQ * QKVD, (size_t)SEQ * QKVD, (size_t)SEQ * SEQ, 0.03125f);

    // 4) row softmax -> bf16 P
    softmax_kernel<<<BATCH * SEQ, 256, 0, stream>>>(scores, P);

    // 5) V transpose (bias already folded in step 2)
    transposeV_kernel<<<dim3(SEQ / 64, HIDDEN / 64, BATCH), 256, 0, stream>>>(qkv, Vt);

    // 6) out = P @ Vt^T per batch (f32 out)  grid 4x16x4 = 256
    gemm_bt<2><<<dim3(HIDDEN / 256, SEQ / 128, BATCH), 512, 0, stream>>>(
        P, Vt, out, nullptr, SEQ, SEQ, SEQ, HIDDEN,
        (size_t)SEQ * SEQ, (size_t)HIDDEN * SEQ, (size_t)SEQ * HIDDEN, 1.f);
}